// Round 6
// baseline (138.904 us; speedup 1.0000x reference)
//
#include <hip/hip_runtime.h>
#include <hip/hip_bf16.h>

// out[b] = Q[b] @ (K[b]^T @ V[b]) / 8      (softmax in ref is dead code)
// B=8, S=2048, D=128, fp32 in/out. bf16 MFMA, 2 kernels + tiny memset:
//  K1: P[b][ch] = K_chunk^T @ V_chunk partials (512 blocks, one 64x128
//      d-half each); last block per (b,half) reduces -> MT[b][c][d] (bf16).
//  K2: out = Q @ M (512 blocks, per-wave 16x64 tile, MT k-contiguous).

#define B 8
#define S 2048
#define D 128
#define CH 32          // s-chunks per batch
#define SC 64          // rows per chunk

typedef __attribute__((ext_vector_type(8))) short short8;
typedef __attribute__((ext_vector_type(4))) float f32x4;

static __device__ __forceinline__ short f2bf(float f) {
    __hip_bfloat16 h = __float2bfloat16(f);      // RNE
    union { __hip_bfloat16 h; short s; } u; u.h = h;
    return u.s;
}
static __device__ __forceinline__ float bf2f(unsigned short s) {
    union { unsigned u; float f; } x; x.u = ((unsigned)s) << 16;
    return x.f;
}

// ---- K1: split-K K^T@V partials + last-block reduce ------------------------
__global__ __launch_bounds__(256) void k1_ktv(
    const float* __restrict__ K, const float* __restrict__ V,
    unsigned short* __restrict__ P, unsigned short* __restrict__ MT,
    int* __restrict__ cnt)
{
    int blk = blockIdx.x;                     // 512
    int b = blk >> 6, rem = blk & 63;
    int ch = rem >> 1, h = rem & 1;           // d-half of the 128x128 output
    const float* Kb = K + ((size_t)b * S + (size_t)ch * SC) * D;
    const float* Vb = V + ((size_t)b * S + (size_t)ch * SC) * D;

    int tid = threadIdx.x;
    int w = tid >> 6, l = tid & 63;
    int lr = l & 15, lg = l >> 4;
    int dr0 = h * 64 + (w >> 1) * 32;         // output rows (K columns)
    int cc0 = (w & 1) * 64;                   // output cols (V columns)

    f32x4 acc[2][4];
#pragma unroll
    for (int i = 0; i < 2; i++)
#pragma unroll
        for (int j = 0; j < 4; j++) acc[i][j] = (f32x4)0.f;

#pragma unroll
    for (int ks = 0; ks < 2; ++ks) {
        int sb = ks * 32 + lg * 8;            // this lane's 8 s-rows
        short8 af[2], bv[4];
#pragma unroll
        for (int fi = 0; fi < 2; ++fi) {      // A = K columns (K^T rows)
            const float* kp = Kb + (size_t)sb * D + dr0 + fi * 16 + lr;
            float t[8];
#pragma unroll
            for (int i = 0; i < 8; ++i) t[i] = kp[(size_t)i * D];
            short8 s8;
#pragma unroll
            for (int i = 0; i < 8; ++i) s8[i] = f2bf(t[i]);
            af[fi] = s8;
        }
#pragma unroll
        for (int fj = 0; fj < 4; ++fj) {      // B = V columns
            const float* vp = Vb + (size_t)sb * D + cc0 + fj * 16 + lr;
            float t[8];
#pragma unroll
            for (int i = 0; i < 8; ++i) t[i] = vp[(size_t)i * D];
            short8 s8;
#pragma unroll
            for (int i = 0; i < 8; ++i) s8[i] = f2bf(t[i]);
            bv[fj] = s8;
        }
#pragma unroll
        for (int fi = 0; fi < 2; ++fi)
#pragma unroll
            for (int fj = 0; fj < 4; ++fj)
                acc[fi][fj] = __builtin_amdgcn_mfma_f32_16x16x32_bf16(
                    af[fi], bv[fj], acc[fi][fj], 0, 0, 0);
    }

    unsigned short* Pb = P + (size_t)(b * CH + ch) * D * D;
#pragma unroll
    for (int fi = 0; fi < 2; ++fi)
#pragma unroll
        for (int fj = 0; fj < 4; ++fj)
#pragma unroll
            for (int j = 0; j < 4; ++j) {
                int row = dr0 + fi * 16 + lg * 4 + j;
                int col = cc0 + fj * 16 + lr;
                Pb[row * D + col] = (unsigned short)f2bf(acc[fi][fj][j]);
            }

    // ---- split-K combine: last block of (b,h) reduces its half of M ------
    __shared__ int amLast;
    __threadfence();                          // release our P stores
    __syncthreads();
    if (tid == 0) {
        int old = __hip_atomic_fetch_add(&cnt[b * 2 + h], 1,
                                         __ATOMIC_ACQ_REL,
                                         __HIP_MEMORY_SCOPE_AGENT);
        amLast = (old == CH - 1);
    }
    __syncthreads();
    if (amLast) {
        __threadfence();                      // acquire others' P stores
        const unsigned short* Pall = P + (size_t)(b * CH) * D * D;
        unsigned short* Mb = MT + (size_t)b * D * D;
#pragma unroll
        for (int it = 0; it < 16; ++it) {     // 4096 (d, c-pair) tasks
            int flat = it * 256 + tid;
            int dl = flat >> 6, cp = flat & 63;
            int d = h * 64 + dl, c = cp * 2;
            float s0 = 0.f, s1 = 0.f;
#pragma unroll 8
            for (int cc = 0; cc < CH; ++cc) {
                unsigned pair = *(const unsigned*)(Pall + (size_t)cc * D * D + d * D + c);
                s0 += bf2f((unsigned short)(pair & 0xFFFF));
                s1 += bf2f((unsigned short)(pair >> 16));
            }
            Mb[c * D + d]       = (unsigned short)f2bf(s0 * 0.125f);
            Mb[(c + 1) * D + d] = (unsigned short)f2bf(s1 * 0.125f);
        }
    }
}

// ---- K2: out[b] = Q[b] @ M[b]  (per-wave 16x64 tile) -----------------------
__global__ __launch_bounds__(256) void k2_qm(
    const float* __restrict__ Q, const unsigned short* __restrict__ MT,
    float* __restrict__ Out)
{
    int blk = blockIdx.x;                  // 512
    int b = blk >> 6, t = blk & 63;        // 64 row-tiles of 32
    int tid = threadIdx.x;
    int w = tid >> 6, l = tid & 63;
    int lr = l & 15, lg = l >> 4;
    int r0 = t * 32 + (w >> 1) * 16;       // wave rows
    int c0 = (w & 1) * 64;                 // wave cols

    const float* Qb = Q + ((size_t)b * S + r0) * D;
    const unsigned short* Mb = MT + (size_t)b * D * D;

    f32x4 acc[4];
#pragma unroll
    for (int j = 0; j < 4; j++) acc[j] = (f32x4)0.f;

#pragma unroll
    for (int ks = 0; ks < 4; ++ks) {
        int k0 = ks * 32 + lg * 8;
        const float* qp = Qb + (size_t)lr * D + k0;
        float4 q0 = *(const float4*)qp;
        float4 q1 = *(const float4*)(qp + 4);
        short8 a;
        a[0] = f2bf(q0.x); a[1] = f2bf(q0.y); a[2] = f2bf(q0.z); a[3] = f2bf(q0.w);
        a[4] = f2bf(q1.x); a[5] = f2bf(q1.y); a[6] = f2bf(q1.z); a[7] = f2bf(q1.w);
#pragma unroll
        for (int fj = 0; fj < 4; ++fj) {
            short8 bb = *(const short8*)(Mb + (size_t)(c0 + fj * 16 + lr) * D + k0);
            acc[fj] = __builtin_amdgcn_mfma_f32_16x16x32_bf16(a, bb, acc[fj], 0, 0, 0);
        }
    }

    float* Ob = Out + ((size_t)b * S + r0) * D;
#pragma unroll
    for (int fj = 0; fj < 4; ++fj)
#pragma unroll
        for (int j = 0; j < 4; ++j)
            Ob[(size_t)(lg * 4 + j) * D + c0 + fj * 16 + lr] = acc[fj][j];
}

extern "C" void kernel_launch(void* const* d_in, const int* in_sizes, int n_in,
                              void* d_out, int out_size, void* d_ws, size_t ws_size,
                              hipStream_t stream)
{
    const float* q = (const float*)d_in[0];
    const float* k = (const float*)d_in[1];
    const float* v = (const float*)d_in[2];
    float* out = (float*)d_out;

    unsigned short* P  = (unsigned short*)d_ws;            // 8 MB
    unsigned short* MT = P + (size_t)B * CH * D * D;       // 256 KB
    int* cnt = (int*)(MT + (size_t)B * D * D);             // 16 ints

    hipMemsetAsync(cnt, 0, 16 * sizeof(int), stream);
    k1_ktv<<<B * CH * 2, 256, 0, stream>>>(k, v, P, MT, cnt);
    k2_qm<<<B * 64, 256, 0, stream>>>(q, MT, out);
}

// Round 7
// 23.749 us; speedup vs baseline: 5.8489x; 5.8489x over previous
//
#include <hip/hip_runtime.h>
#include <hip/hip_bf16.h>

// out[b] = Q[b] @ (K[b]^T @ V[b]) / 8      (softmax in ref is dead code)
// B=8, S=2048, D=128, fp32 in/out. bf16 MFMA, 2 kernels, NO sync primitives:
//  K1: P[b][ch] (bf16) = K_chunk^T @ V_chunk, CH=8 chunks of 256 rows,
//      d-half split -> 128 blocks x 512 thr (8 waves, 32x32 wave tiles).
//  K2: per-block re-reduce of the batch's 8 partials (L2-hot) -> swizzled
//      transposed LDS M -> Q @ M (64 rows/block, 256 blocks).
// Device-scope fences/atomics are POISON on 8-XCD gfx950 (R4/R6 evidence).

#define B 8
#define S 2048
#define D 128
#define CH 8           // s-chunks per batch
#define SC 256         // rows per chunk

typedef __attribute__((ext_vector_type(8))) short short8;
typedef __attribute__((ext_vector_type(4))) float f32x4;

static __device__ __forceinline__ short f2bf(float f) {
    __hip_bfloat16 h = __float2bfloat16(f);      // RNE
    union { __hip_bfloat16 h; short s; } u; u.h = h;
    return u.s;
}
static __device__ __forceinline__ float bf2f(unsigned short s) {
    union { unsigned u; float f; } x; x.u = ((unsigned)s) << 16;
    return x.f;
}

// ---- K1: P[b][ch] (bf16) = K_chunk^T @ V_chunk -----------------------------
__global__ __launch_bounds__(512) void k1_ktv(
    const float* __restrict__ K, const float* __restrict__ V,
    unsigned short* __restrict__ P)
{
    int blk = blockIdx.x;                     // 128 = 8b x 8ch x 2h
    int b = blk >> 4, rem = blk & 15;
    int ch = rem >> 1, h = rem & 1;           // d-half of the 128x128 output
    const float* Kb = K + ((size_t)b * S + (size_t)ch * SC) * D;
    const float* Vb = V + ((size_t)b * S + (size_t)ch * SC) * D;

    int tid = threadIdx.x;
    int w = tid >> 6, l = tid & 63;
    int lr = l & 15, lg = l >> 4;
    int dr0 = h * 64 + (w >> 2) * 32;         // output rows (K columns)
    int cc0 = (w & 3) * 32;                   // output cols (V columns)

    f32x4 acc[2][2];
#pragma unroll
    for (int i = 0; i < 2; i++)
#pragma unroll
        for (int j = 0; j < 2; j++) acc[i][j] = (f32x4)0.f;

    for (int ks = 0; ks < 8; ++ks) {
        int sb = ks * 32 + lg * 8;            // this lane's 8 s-rows
        short8 af[2], bv[2];
#pragma unroll
        for (int fi = 0; fi < 2; ++fi) {      // A = K columns (K^T rows)
            const float* kp = Kb + (size_t)sb * D + dr0 + fi * 16 + lr;
            float t[8];
#pragma unroll
            for (int i = 0; i < 8; ++i) t[i] = kp[(size_t)i * D];
            short8 s8;
#pragma unroll
            for (int i = 0; i < 8; ++i) s8[i] = f2bf(t[i]);
            af[fi] = s8;
        }
#pragma unroll
        for (int fj = 0; fj < 2; ++fj) {      // B = V columns
            const float* vp = Vb + (size_t)sb * D + cc0 + fj * 16 + lr;
            float t[8];
#pragma unroll
            for (int i = 0; i < 8; ++i) t[i] = vp[(size_t)i * D];
            short8 s8;
#pragma unroll
            for (int i = 0; i < 8; ++i) s8[i] = f2bf(t[i]);
            bv[fj] = s8;
        }
#pragma unroll
        for (int fi = 0; fi < 2; ++fi)
#pragma unroll
            for (int fj = 0; fj < 2; ++fj)
                acc[fi][fj] = __builtin_amdgcn_mfma_f32_16x16x32_bf16(
                    af[fi], bv[fj], acc[fi][fj], 0, 0, 0);
    }

    unsigned short* Pb = P + (size_t)(b * CH + ch) * D * D;
#pragma unroll
    for (int fi = 0; fi < 2; ++fi)
#pragma unroll
        for (int fj = 0; fj < 2; ++fj)
#pragma unroll
            for (int j = 0; j < 4; ++j) {
                int row = dr0 + fi * 16 + lg * 4 + j;
                int col = cc0 + fj * 16 + lr;
                Pb[row * D + col] = (unsigned short)f2bf(acc[fi][fj][j]);
            }
}

// ---- K2: re-reduce partials -> LDS M^T (swizzled) -> out = Q @ M -----------
__global__ __launch_bounds__(256) void k2_rqm(
    const float* __restrict__ Q, const unsigned short* __restrict__ P,
    float* __restrict__ Out)
{
    __shared__ unsigned short MT[D * D];       // 32 KB, byte-swizzled [c][k]

    int blk = blockIdx.x;                      // 256 = 8b x 32 row-tiles
    int b = blk >> 5, t = blk & 31;
    int tid = threadIdx.x;

    // ---- phase 1: reduce 8 partials; thread owns d0..d0+8 x c0..c0+8 ------
    int cblk = tid & 15, dblk = tid >> 4;
    int c0 = cblk * 8, d0 = dblk * 8;
    const unsigned short* Pb = P + (size_t)(b * CH) * D * D;

    float m[8][8];                             // [j = d-local][i = c-local]
#pragma unroll
    for (int j = 0; j < 8; ++j)
#pragma unroll
        for (int i = 0; i < 8; ++i) m[j][i] = 0.f;

#pragma unroll
    for (int cc = 0; cc < CH; ++cc) {
#pragma unroll
        for (int j = 0; j < 8; ++j) {
            short8 pv = *(const short8*)(Pb + (size_t)cc * D * D + (d0 + j) * D + c0);
#pragma unroll
            for (int i = 0; i < 8; ++i)
                m[j][i] += bf2f((unsigned short)pv[i]);
        }
    }

    // ---- phase 2: write M^T (x 1/8) to LDS, swizzled -----------------------
    // byte(c, k-octet dblk') = (c*256 + 16*dblk') ^ (X(c)<<4),
    // X(c) = (c&7) ^ ((c>>3)&7); consistent bijection with phase-3 reads.
    char* mt = (char*)MT;
#pragma unroll
    for (int i = 0; i < 8; ++i) {
        int c = c0 + i;
        short8 sv;
#pragma unroll
        for (int j = 0; j < 8; ++j) sv[j] = f2bf(m[j][i] * 0.125f);
        int X = ((c & 7) ^ (cblk & 7)) & 7;    // cblk == c>>3 here
        int byte = (c * 256 + 2 * d0) ^ (X << 4);
        *(short8*)(mt + byte) = sv;
    }
    __syncthreads();

    // ---- phase 3: out rows r0..r0+16 per wave = Q @ M ----------------------
    int w = tid >> 6, l = tid & 63;
    int lr = l & 15, lg = l >> 4;
    int r0 = t * 64 + w * 16;

    const float* Qb = Q + ((size_t)b * S + r0) * D;

    f32x4 acc[8];
#pragma unroll
    for (int j = 0; j < 8; ++j) acc[j] = (f32x4)0.f;

#pragma unroll
    for (int ks = 0; ks < 4; ++ks) {
        int k0 = ks * 32 + lg * 8;
        const float* qp = Qb + (size_t)lr * D + k0;
        float4 q0 = *(const float4*)qp;
        float4 q1 = *(const float4*)(qp + 4);
        short8 a;
        a[0] = f2bf(q0.x); a[1] = f2bf(q0.y); a[2] = f2bf(q0.z); a[3] = f2bf(q0.w);
        a[4] = f2bf(q1.x); a[5] = f2bf(q1.y); a[6] = f2bf(q1.z); a[7] = f2bf(q1.w);
#pragma unroll
        for (int fj = 0; fj < 8; ++fj) {
            int c = fj * 16 + lr;
            int X = ((c & 7) ^ ((c >> 3) & 7)) & 7;
            int byte = (c * 256 + 2 * k0) ^ (X << 4);
            short8 bb = *(const short8*)(mt + byte);
            acc[fj] = __builtin_amdgcn_mfma_f32_16x16x32_bf16(a, bb, acc[fj], 0, 0, 0);
        }
    }

    float* Ob = Out + ((size_t)b * S + r0) * D;
#pragma unroll
    for (int fj = 0; fj < 8; ++fj)
#pragma unroll
        for (int j = 0; j < 4; ++j)
            Ob[(size_t)(lg * 4 + j) * D + fj * 16 + lr] = acc[fj][j];
}

extern "C" void kernel_launch(void* const* d_in, const int* in_sizes, int n_in,
                              void* d_out, int out_size, void* d_ws, size_t ws_size,
                              hipStream_t stream)
{
    const float* q = (const float*)d_in[0];
    const float* k = (const float*)d_in[1];
    const float* v = (const float*)d_in[2];
    float* out = (float*)d_out;

    unsigned short* P = (unsigned short*)d_ws;         // 2 MB bf16 partials

    k1_ktv<<<B * CH * 2, 512, 0, stream>>>(k, v, P);
    k2_rqm<<<B * 32, 256, 0, stream>>>(q, P, out);
}